// Round 1
// baseline (168.070 us; speedup 1.0000x reference)
//
#include <hip/hip_runtime.h>
#include <hip/hip_bf16.h>

// Problem constants (match reference setup_inputs)
#define Bn 8
#define Nn 131072
#define Cn 20
#define Kn 20

#define THREADS 256
#define CHUNK 2048            // elements per block (contiguous)
#define EPB (CHUNK / THREADS) // 8 elements per thread
#define BLOCKS_PER_BATCH (Nn / CHUNK) // 64
#define GRID (Bn * BLOCKS_PER_BATCH)  // 512

// ws layout (floats):
// [0 .. B*K*4)   segment accumulators: x,y,z,count per (b,k)
// [B*K*4]        sem_sum
// [B*K*4 + 1]    csv_sum
#define WS_SEG 0
#define WS_SEM (Bn * Kn * 4)
#define WS_CSV (Bn * Kn * 4 + 1)
#define WS_FLOATS (Bn * Kn * 4 + 2)

// Pass 1: sem-loss gather-sum + per-(b,k) point sums & counts.
__global__ void __launch_bounds__(THREADS) loss_pass1(
    const float* __restrict__ points,
    const float* __restrict__ sem,
    const int* __restrict__ label,
    float* __restrict__ ws) {
    // wave-replicated LDS bins to cut LDS-atomic contention (4 waves/block)
    __shared__ float acc[4][Kn][4];
    __shared__ float wsum[4];

    const int tid  = threadIdx.x;
    const int wave = tid >> 6;
    const int lane = tid & 63;

    for (int i = tid; i < 4 * Kn * 4; i += THREADS) ((float*)acc)[i] = 0.0f;
    __syncthreads();

    const int b  = blockIdx.x / BLOCKS_PER_BATCH;
    const int n0 = (blockIdx.x % BLOCKS_PER_BATCH) * CHUNK;
    const int* lab = label + (long)b * 2 * Nn;

    float semsum = 0.0f;
#pragma unroll
    for (int e = 0; e < EPB; ++e) {
        const int n    = n0 + e * THREADS + tid;
        const int cls  = lab[n];
        const int inst = lab[Nn + n];
        const long rowbase = ((long)b * Nn + n);
        semsum += sem[rowbase * Cn + cls];
        const float x = points[rowbase * 3 + 0];
        const float y = points[rowbase * 3 + 1];
        const float z = points[rowbase * 3 + 2];
        atomicAdd(&acc[wave][inst][0], x);
        atomicAdd(&acc[wave][inst][1], y);
        atomicAdd(&acc[wave][inst][2], z);
        atomicAdd(&acc[wave][inst][3], 1.0f);
    }
    __syncthreads();

    // flush combined wave copies -> global (only this batch's 80 bins)
    for (int i = tid; i < Kn * 4; i += THREADS) {
        const int k = i >> 2, f = i & 3;
        const float v = acc[0][k][f] + acc[1][k][f] + acc[2][k][f] + acc[3][k][f];
        atomicAdd(&ws[WS_SEG + (b * Kn + k) * 4 + f], v);
    }

    // block-reduce semsum, one atomic per block
#pragma unroll
    for (int off = 32; off > 0; off >>= 1) semsum += __shfl_down(semsum, off);
    if (lane == 0) wsum[wave] = semsum;
    __syncthreads();
    if (tid == 0) atomicAdd(&ws[WS_SEM], wsum[0] + wsum[1] + wsum[2] + wsum[3]);
}

// Pass 2: centers = sum/max(cnt,1); csv loss sum.
__global__ void __launch_bounds__(THREADS) loss_pass2(
    const float* __restrict__ points,
    const float* __restrict__ pcsv,
    const int* __restrict__ label,
    float* __restrict__ ws) {
    __shared__ float ctr[Kn][3];
    __shared__ float wsum[4];

    const int tid  = threadIdx.x;
    const int wave = tid >> 6;
    const int lane = tid & 63;
    const int b    = blockIdx.x / BLOCKS_PER_BATCH;

    if (tid < Kn) {
        const float* s = ws + WS_SEG + (b * Kn + tid) * 4;
        const float inv = 1.0f / fmaxf(s[3], 1.0f);
        ctr[tid][0] = s[0] * inv;
        ctr[tid][1] = s[1] * inv;
        ctr[tid][2] = s[2] * inv;
    }
    __syncthreads();

    const int n0 = (blockIdx.x % BLOCKS_PER_BATCH) * CHUNK;
    const int* inst_lab = label + (long)b * 2 * Nn + Nn;

    float lsum = 0.0f;
#pragma unroll
    for (int e = 0; e < EPB; ++e) {
        const int n    = n0 + e * THREADS + tid;
        const int inst = inst_lab[n];
        const long base = ((long)b * Nn + n) * 3;
        const float px = points[base + 0];
        const float py = points[base + 1];
        const float pz = points[base + 2];
        const float dx = ctr[inst][0] - px;
        const float dy = ctr[inst][1] - py;
        const float dz = ctr[inst][2] - pz;
        const float nd = sqrtf(dx * dx + dy * dy + dz * dz);
        const float w  = fminf(nd, 1.0f);
        const float ex = dx - pcsv[base + 0];
        const float ey = dy - pcsv[base + 1];
        const float ez = dz - pcsv[base + 2];
        lsum += sqrtf(ex * ex + ey * ey + ez * ez) * w;
    }

#pragma unroll
    for (int off = 32; off > 0; off >>= 1) lsum += __shfl_down(lsum, off);
    if (lane == 0) wsum[wave] = lsum;
    __syncthreads();
    if (tid == 0) atomicAdd(&ws[WS_CSV], wsum[0] + wsum[1] + wsum[2] + wsum[3]);
}

// Finalize: out = -sem_mean + 0.2 * csv_mean
__global__ void loss_final(const float* __restrict__ ws, float* __restrict__ out) {
    const float invBN = 1.0f / (float)((long)Bn * Nn);
    out[0] = -ws[WS_SEM] * invBN + 0.2f * ws[WS_CSV] * invBN;
}

extern "C" void kernel_launch(void* const* d_in, const int* in_sizes, int n_in,
                              void* d_out, int out_size, void* d_ws, size_t ws_size,
                              hipStream_t stream) {
    const float* points = (const float*)d_in[0];
    const float* sem    = (const float*)d_in[1];
    const float* pcsv   = (const float*)d_in[2];
    const int*   label  = (const int*)d_in[3];
    float* ws  = (float*)d_ws;
    float* out = (float*)d_out;

    hipMemsetAsync(d_ws, 0, WS_FLOATS * sizeof(float), stream);
    loss_pass1<<<GRID, THREADS, 0, stream>>>(points, sem, label, ws);
    loss_pass2<<<GRID, THREADS, 0, stream>>>(points, pcsv, label, ws);
    loss_final<<<1, 1, 0, stream>>>(ws, out);
}